// Round 9
// baseline (187.613 us; speedup 1.0000x reference)
//
#include <hip/hip_runtime.h>
#include <hip/hip_bf16.h>
#include <math.h>

// VOCAB=50000, EMBED=256, MAXLEN=512, UNITS=32, F1=16, BATCH=512.
#define TT 512
#define BB 512
#define EE 256
#define UU 32
#define FF1 16
#define NWAVE 2048            // proj waves: 8/CU, 2/SIMD (best e2e config, R2)

// 2*log2(e): pre-scale factor so tanh needs no leading multiply.
#define TWO_LOG2E 2.8853900817779268f

__device__ __forceinline__ float rdlane(float v, int lane) {
    return __int_as_float(__builtin_amdgcn_readlane(__float_as_int(v), lane));
}

// v += value from lane (i - N) within the 16-lane DPP row (0 past row edge).
#define DPP_ADD(v, ctrl)                                                    \
    (v) += __int_as_float(__builtin_amdgcn_update_dpp(                      \
        0, __float_as_int(v), (ctrl), 0xf, 0xf, true))

// ---------------------------------------------------------------------------
// Kernel A: P[r][u] = 0.5*(2log2e*(emb[r]@Wx[:,u] + bias[u]) + S_u),
// S_u = 2log2e * colsum(Wh)[u].  The 0.5 and +S_u feed kernel B's split-k
// r-fold scan: each half-row adds P once, the cross-row combine doubles it
// back to (x' + S').  DPP-reduce GEMV, near memory floor.
// ---------------------------------------------------------------------------
__global__ __launch_bounds__(64) void proj_dpp(
    const float* __restrict__ emb, const float* __restrict__ Wx,
    const float* __restrict__ bias, const float* __restrict__ Wh,
    float* __restrict__ P, int nrows)
{
    const int L = threadIdx.x;
    const int g = L >> 4;              // u-octet 0..3
    const int c = L & 15;              // k-lane 0..15
    const int wv = blockIdx.x;         // 0..NWAVE-1

    // ---- one-time coalesced w preload: w[kk][uu] = Wx[c+16*kk][g*8+uu]
    float w[16][8];
    #pragma unroll
    for (int kk = 0; kk < 16; ++kk) {
        const float4* src = (const float4*)(Wx + (size_t)(kk * 16 + c) * UU + g * 8);
        float4 a = src[0], b = src[1];
        w[kk][0] = a.x; w[kk][1] = a.y; w[kk][2] = a.z; w[kk][3] = a.w;
        w[kk][4] = b.x; w[kk][5] = b.y; w[kk][6] = b.z; w[kk][7] = b.w;
    }
    // bs'[uu] = 0.5*2log2e*(bias[u] + colsum(Wh)[u])  (S-fold, once per block)
    float bs[8];
    #pragma unroll
    for (int uu = 0; uu < 8; ++uu) {
        const int ucol = g * 8 + uu;
        float s = 0.f;
        for (int k = 0; k < UU; ++k) s += Wh[k * UU + ucol];
        bs[uu] = 0.5f * TWO_LOG2E * (bias[ucol] + s);
    }

    // rows handled by this wave: r = wv + NWAVE*i
    auto rowptr = [&](int i) {
        int r = wv + NWAVE * i;
        if (r >= nrows) r = nrows - 1;             // clamped dummy
        return emb + (size_t)r * EE;
    };

    float xA[16], xB[16];
    {
        const float* rp = rowptr(0);
        #pragma unroll
        for (int kk = 0; kk < 16; ++kk) xA[kk] = rp[kk * 16 + c];
    }

    const int NI = (nrows - 1 - wv) / NWAVE + 1;   // #valid rows (wv < nrows)

    for (int i = 0; i < NI; ++i) {
        // prefetch next row (clamped at tail)
        {
            const float* rp = rowptr(i + 1 < NI ? i + 1 : i);
            #pragma unroll
            for (int kk = 0; kk < 16; ++kk) xB[kk] = rp[kk * 16 + c];
        }

        // partials for this lane's 16 k's x 8 u's
        float p[8];
        #pragma unroll
        for (int uu = 0; uu < 8; ++uu) p[uu] = 0.f;
        #pragma unroll
        for (int kk = 0; kk < 16; ++kk) {
            const float xk = xA[kk];
            #pragma unroll
            for (int uu = 0; uu < 8; ++uu)
                p[uu] = fmaf(xk, w[kk][uu], p[uu]);
        }

        // reduce over the 16 c-lanes (DPP row-of-16); lane c==15 holds sums
        #pragma unroll
        for (int uu = 0; uu < 8; ++uu) {
            DPP_ADD(p[uu], 0x111);   // row_shr:1
            DPP_ADD(p[uu], 0x112);   // row_shr:2
            DPP_ADD(p[uu], 0x114);   // row_shr:4
            DPP_ADD(p[uu], 0x118);   // row_shr:8
        }

        if (c == 15) {
            const int r = wv + NWAVE * i;
            const float c0 = 0.5f * TWO_LOG2E;
            float4 o0, o1;
            o0.x = fmaf(p[0], c0, bs[0]);
            o0.y = fmaf(p[1], c0, bs[1]);
            o0.z = fmaf(p[2], c0, bs[2]);
            o0.w = fmaf(p[3], c0, bs[3]);
            o1.x = fmaf(p[4], c0, bs[4]);
            o1.y = fmaf(p[5], c0, bs[5]);
            o1.z = fmaf(p[6], c0, bs[6]);
            o1.w = fmaf(p[7], c0, bs[7]);
            float4* dst = (float4*)(P + (size_t)r * UU + g * 8);
            dst[0] = o0; dst[1] = o1;
        }

        #pragma unroll
        for (int kk = 0; kk < 16; ++kk) xA[kk] = xB[kk];
    }
}

// ---------------------------------------------------------------------------
// Kernel B v14: split-k DPP-fused scan + r-fold.
// Model (fit v6/v8/v11/v13): T ≈ 1.7cy x N_instr + 215cy serial floor.
// v13 = 43 slots (288cy). v14 removes the 2x duplicated MACs: each 16-row
// computes one (u-half x k-half) quadrant = 16 fused-DPP FMAs (was 32);
// partials combined by ONE permlane16_swap + add (a=b symmetric usage: the
// pA+pB sum is IMMUNE to swap-direction convention). Broadcast state is
// r = rcp(exp2(a)+1) (r-fold: h=1-2r folded into wr=-2*wh and proj's +S),
// dropping the tail fma. ~32 slots/step.
//   state layout (v13-verified): lane L holds r_u, u=(L&15)+16*(L>>5)
//     -> 16-rows = [rLo, rLo, rHi, rHi]
//   swap32 (v11/v13-verified direction): A=lo-dup, B=hi-dup
//   H = oddrow16 ? B : A -> rows [A,B,A,B]: row parity = its k-half ✓
//   quadrants: r0:u0-15xkLo r1:u0-15xkHi r2:u16-31xkLo r3:u16-31xkHi;
//   permlane16 combine sums row pairs (0,1),(2,3) -> [aLo,aLo,aHi,aHi] ✓
//   x' and S' enter once per half-row as P''=0.5(x'+S'), doubled by combine.
// ---------------------------------------------------------------------------
__global__ __launch_bounds__(64) void scan_heads(
    const int* __restrict__ tokens, const float* __restrict__ P,
    const float* __restrict__ Wh,
    const float* __restrict__ W1, const float* __restrict__ b1,
    const float* __restrict__ W2, const float* __restrict__ b2,
    float* __restrict__ out)
{
    __shared__ float xs[TT * UU];      // 512 rows x 128 B = 64 KB

    const int L = threadIdx.x;
    const int c = L & 15;
    const int khalf = ((L >> 4) & 1) << 4;   // k-half this row accumulates
    const int u = c + ((L >> 5) << 4);       // state/output index owned
    const bool oddrow = ((L >> 4) & 1) != 0;
    const int b = blockIdx.x;
    const int* trow = tokens + b * TT;

    // ---- probe row_ror direction (v11/v13-verified) ----
    int probe = __builtin_amdgcn_update_dpp(0, c, 0x121, 0xf, 0xf, true);
    const int kstep = (__builtin_amdgcn_readfirstlane(probe) == 15) ? -1 : 1;

    // wr[jj] pairs with ror_jj(H): k = ((c+kstep*jj)&15) + khalf
    // wr = -2 * 2log2e * Wh[k][u]   (r-fold weights)
    float wr[16];
    #pragma unroll
    for (int jj = 0; jj < 16; ++jj) {
        const int kj = ((c + kstep * jj) & 15) + khalf;
        wr[jj] = -2.0f * TWO_LOG2E * Wh[kj * UU + u];
    }

    // ---- gather phase: 64 global_load_lds instrs, 8 tokens each ----
    const int sub = L >> 3;            // token-within-group
    const int q   = L & 7;             // 16-B chunk within the 128-B row
    for (int cc = 0; cc < 8; ++cc) {
        int tk8[8];
        #pragma unroll
        for (int i = 0; i < 8; ++i)
            tk8[i] = trow[cc * 64 + i * 8 + sub];
        #pragma unroll
        for (int i = 0; i < 8; ++i) {
            const float* src = P + (size_t)tk8[i] * UU + q * 4;
            float* dst = xs + (cc * 64 + i * 8) * UU;   // wave-uniform base
            __builtin_amdgcn_global_load_lds(
                (const __attribute__((address_space(1))) void*)src,
                (__attribute__((address_space(3))) void*)dst, 16, 0, 0);
        }
    }
    __syncthreads();   // drains vmcnt: all LDS rows resident

    // ---- scan ----
    float xr[8];
    #pragma unroll
    for (int j = 0; j < 8; ++j) xr[j] = xs[j * UU + u];   // = 0.5*(x'+S')

    float r = 0.5f;                    // h = 0  =>  r = 0.5

    for (int t = 0; t < TT; t += 8) {
        // block prefetch: 8 conflict-free ds_read_b32, consumed 8 steps later
        float xn[8];
        #pragma unroll
        for (int j = 0; j < 8; ++j)
            xn[j] = xs[((t + 8 + j) & (TT - 1)) * UU + u];

        #pragma unroll
        for (int j = 0; j < 8; ++j) {
            // A = rLo dup everywhere, Bv = rHi dup (v13-verified direction)
            float A  = r;
            float Bv = r;
            asm("s_nop 1\n\t"
                "v_permlane32_swap_b32 %0, %1\n\t"
                "s_nop 1"
                : "+v"(A), "+v"(Bv));
            // per-row k-half source
            float H = oddrow ? Bv : A;

            // 16 fused-DPP FMAs, 4 accs depth 4; x (=0.5(x'+S')) in acc0
            float p0, p1, p2, p3;
            asm("s_nop 1\n\t"
                "v_fma_f32  %0, %4, %6, %5\n\t"
                "v_mul_f32  %1, %4, %7  row_ror:1\n\t"
                "v_mul_f32  %2, %4, %8  row_ror:2\n\t"
                "v_mul_f32  %3, %4, %9  row_ror:3\n\t"
                "v_fmac_f32 %0, %4, %10 row_ror:4\n\t"
                "v_fmac_f32 %1, %4, %11 row_ror:5\n\t"
                "v_fmac_f32 %2, %4, %12 row_ror:6\n\t"
                "v_fmac_f32 %3, %4, %13 row_ror:7\n\t"
                "v_fmac_f32 %0, %4, %14 row_ror:8\n\t"
                "v_fmac_f32 %1, %4, %15 row_ror:9\n\t"
                "v_fmac_f32 %2, %4, %16 row_ror:10\n\t"
                "v_fmac_f32 %3, %4, %17 row_ror:11\n\t"
                "v_fmac_f32 %0, %4, %18 row_ror:12\n\t"
                "v_fmac_f32 %1, %4, %19 row_ror:13\n\t"
                "v_fmac_f32 %2, %4, %20 row_ror:14\n\t"
                "v_fmac_f32 %3, %4, %21 row_ror:15"
                : "=&v"(p0), "=&v"(p1), "=&v"(p2), "=&v"(p3)
                : "v"(H), "v"(xr[j]),
                  "v"(wr[0]),  "v"(wr[1]),  "v"(wr[2]),  "v"(wr[3]),
                  "v"(wr[4]),  "v"(wr[5]),  "v"(wr[6]),  "v"(wr[7]),
                  "v"(wr[8]),  "v"(wr[9]),  "v"(wr[10]), "v"(wr[11]),
                  "v"(wr[12]), "v"(wr[13]), "v"(wr[14]), "v"(wr[15]));

            float p = (p0 + p1) + (p2 + p3);

            // combine across row pairs (0,1),(2,3): pA+pB is direction-immune
            float pA = p, pB = p;
            asm("s_nop 1\n\t"
                "v_permlane16_swap_b32 %0, %1\n\t"
                "s_nop 1"
                : "+v"(pA), "+v"(pB));

            float e = __builtin_amdgcn_exp2f(pA + pB);
            r = __builtin_amdgcn_rcpf(e + 1.0f);
            xr[j] = xn[j];
        }
    }

    float h = fmaf(-2.0f, r, 1.0f);    // materialize h once for the heads

    // ---- fused heads (layout-aware: h_k lives at lane (k&15)+((k>>4)<<5)) --
    const int jh = L & 15;
    float s = b1[jh];
    #pragma unroll
    for (int k = 0; k < UU; ++k) {
        float hk = rdlane(h, (k & 15) + ((k >> 4) << 5));
        s = fmaf(hk, W1[k * FF1 + jh], s);
    }
    float z = b2[0];
    #pragma unroll
    for (int jj = 0; jj < FF1; ++jj) {
        float yj = rdlane(s, jj);      // s duplicated across 16-rows
        z = fmaf(yj, W2[jj], z);
    }
    if (L == 0) {
        float e = __builtin_amdgcn_exp2f(-z * 1.4426950408889634f); // e^{-z}
        out[b] = __builtin_amdgcn_rcpf(1.0f + e);
    }
}

// ---------------------------------------------------------------------------
extern "C" void kernel_launch(void* const* d_in, const int* in_sizes, int n_in,
                              void* d_out, int out_size, void* d_ws, size_t ws_size,
                              hipStream_t stream) {
    const int*   tokens = (const int*)  d_in[0];
    const float* emb    = (const float*)d_in[1];
    const float* Wx     = (const float*)d_in[2];
    const float* Wh     = (const float*)d_in[3];
    const float* bias   = (const float*)d_in[4];
    const float* W1     = (const float*)d_in[5];
    const float* b1     = (const float*)d_in[6];
    const float* W2     = (const float*)d_in[7];
    const float* b2     = (const float*)d_in[8];
    float* out = (float*)d_out;

    const int vocab = in_sizes[1] / EE;        // 50000
    float* P = (float*)d_ws;                   // vocab*32*4 = 6.4 MB

    // A: 2048 single-wave blocks, ~25 rows each (8 waves/CU)
    proj_dpp<<<dim3(NWAVE), dim3(64), 0, stream>>>(
        emb, Wx, bias, Wh, P, vocab);

    // B: 1 batch row per wave -> 512 blocks x 64 threads (2 blocks/CU)
    scan_heads<<<dim3(BB), dim3(64), 0, stream>>>(
        tokens, P, Wh, W1, b1, W2, b2, out);
}

// Round 10
// 169.950 us; speedup vs baseline: 1.1039x; 1.1039x over previous
//
#include <hip/hip_runtime.h>
#include <hip/hip_bf16.h>
#include <math.h>

// VOCAB=50000, EMBED=256, MAXLEN=512, UNITS=32, F1=16, BATCH=512.
#define TT 512
#define BB 512
#define EE 256
#define UU 32
#define FF1 16
#define NWAVE 2048            // proj waves: 8/CU, 2/SIMD (best e2e config, R2)

// 2*log2(e): pre-scale factor so tanh needs no leading multiply.
#define TWO_LOG2E 2.8853900817779268f

__device__ __forceinline__ float rdlane(float v, int lane) {
    return __int_as_float(__builtin_amdgcn_readlane(__float_as_int(v), lane));
}

// v += value from lane (i - N) within the 16-lane DPP row (0 past row edge).
#define DPP_ADD(v, ctrl)                                                    \
    (v) += __int_as_float(__builtin_amdgcn_update_dpp(                      \
        0, __float_as_int(v), (ctrl), 0xf, 0xf, true))

// ---------------------------------------------------------------------------
// Kernel A v15: P[r][u] = 0.5*2log2e*(emb[r]@Wx[:,u] + bias[u])  (= 0.5*x').
// R2-proven body (NO Wh colsum — that regression moved to scan's setup where
// it's 512 blocks x 15 adds instead of 2048 x 256 loads).
// NEW: 3-buffer prefetch — loads issued 2 rows (~840cy compute) ahead, to
// cover the ~900cy HBM latency that made R9's proj 59us (544 GB/s, VALUBusy
// 17.5%: latency-bound with 1-row lookahead).
// ---------------------------------------------------------------------------
__global__ __launch_bounds__(64) void proj_dpp(
    const float* __restrict__ emb, const float* __restrict__ Wx,
    const float* __restrict__ bias, float* __restrict__ P, int nrows)
{
    const int L = threadIdx.x;
    const int g = L >> 4;              // u-octet 0..3
    const int c = L & 15;              // k-lane 0..15
    const int wv = blockIdx.x;         // 0..NWAVE-1

    // ---- one-time coalesced w preload: w[kk][uu] = Wx[c+16*kk][g*8+uu]
    float w[16][8];
    #pragma unroll
    for (int kk = 0; kk < 16; ++kk) {
        const float4* src = (const float4*)(Wx + (size_t)(kk * 16 + c) * UU + g * 8);
        float4 a = src[0], b = src[1];
        w[kk][0] = a.x; w[kk][1] = a.y; w[kk][2] = a.z; w[kk][3] = a.w;
        w[kk][4] = b.x; w[kk][5] = b.y; w[kk][6] = b.z; w[kk][7] = b.w;
    }
    float bs[8];
    #pragma unroll
    for (int uu = 0; uu < 8; ++uu) bs[uu] = bias[g * 8 + uu];

    const int NI = (nrows - 1 - wv) / NWAVE + 1;   // #valid rows (wv < nrows)

    auto rowptr = [&](int i) {
        int r = wv + NWAVE * i;
        if (r >= nrows) r = nrows - 1;             // clamped dummy (reads ok)
        return emb + (size_t)r * EE;
    };
    auto loadrow = [&](float (&x)[16], int i) {
        const float* rp = rowptr(i);
        #pragma unroll
        for (int kk = 0; kk < 16; ++kk) x[kk] = rp[kk * 16 + c];
    };
    auto comp = [&](const float (&x)[16], int i) {
        float p[8];
        #pragma unroll
        for (int uu = 0; uu < 8; ++uu) p[uu] = 0.f;
        #pragma unroll
        for (int kk = 0; kk < 16; ++kk) {
            const float xk = x[kk];
            #pragma unroll
            for (int uu = 0; uu < 8; ++uu)
                p[uu] = fmaf(xk, w[kk][uu], p[uu]);
        }
        // reduce over the 16 c-lanes (DPP row-of-16); lane c==15 holds sums
        #pragma unroll
        for (int uu = 0; uu < 8; ++uu) {
            DPP_ADD(p[uu], 0x111);   // row_shr:1
            DPP_ADD(p[uu], 0x112);   // row_shr:2
            DPP_ADD(p[uu], 0x114);   // row_shr:4
            DPP_ADD(p[uu], 0x118);   // row_shr:8
        }
        if (c == 15) {
            const int r = wv + NWAVE * i;
            const float c0 = 0.5f * TWO_LOG2E;
            float4 o0, o1;
            o0.x = (p[0] + bs[0]) * c0;
            o0.y = (p[1] + bs[1]) * c0;
            o0.z = (p[2] + bs[2]) * c0;
            o0.w = (p[3] + bs[3]) * c0;
            o1.x = (p[4] + bs[4]) * c0;
            o1.y = (p[5] + bs[5]) * c0;
            o1.z = (p[6] + bs[6]) * c0;
            o1.w = (p[7] + bs[7]) * c0;
            float4* dst = (float4*)(P + (size_t)r * UU + g * 8);
            dst[0] = o0; dst[1] = o1;
        }
    };

    // 3-buffer rotation: loads run 2 rows ahead of compute.
    float b0[16], b1[16], b2[16];
    loadrow(b0, 0);
    loadrow(b1, 1);
    int i = 0;
    while (true) {
        loadrow(b2, i + 2);
        comp(b0, i);
        if (++i >= NI) break;
        loadrow(b0, i + 2);
        comp(b1, i);
        if (++i >= NI) break;
        loadrow(b1, i + 2);
        comp(b2, i);
        if (++i >= NI) break;
    }
}

// ---------------------------------------------------------------------------
// Kernel B v15: split-k DPP-fused scan + r-fold (v14 core, verified absmax
// 0.0 @ 57.0us = 267cy/step; model 1.7xN+215 predicts 269 ✓).
// CHANGE vs v14: the S'-half term no longer rides in P (proj reverted); each
// lane computes Shalf = -0.5 * sum_jj wr[jj] ONCE (its k-half's column sum)
// and folds it into the off-chain xr prefetch adds. Identical algebra:
//   row contributes 0.5x' + S'_half + sum_half r*wr; permlane16 combine
//   doubles/sums -> x' + S' + sum_all r*wr = a'.
// ---------------------------------------------------------------------------
__global__ __launch_bounds__(64) void scan_heads(
    const int* __restrict__ tokens, const float* __restrict__ P,
    const float* __restrict__ Wh,
    const float* __restrict__ W1, const float* __restrict__ b1,
    const float* __restrict__ W2, const float* __restrict__ b2,
    float* __restrict__ out)
{
    __shared__ float xs[TT * UU];      // 512 rows x 128 B = 64 KB

    const int L = threadIdx.x;
    const int c = L & 15;
    const int khalf = ((L >> 4) & 1) << 4;   // k-half this row accumulates
    const int u = c + ((L >> 5) << 4);       // state/output index owned
    const bool oddrow = ((L >> 4) & 1) != 0;
    const int b = blockIdx.x;
    const int* trow = tokens + b * TT;

    // ---- probe row_ror direction (v11/v13-verified) ----
    int probe = __builtin_amdgcn_update_dpp(0, c, 0x121, 0xf, 0xf, true);
    const int kstep = (__builtin_amdgcn_readfirstlane(probe) == 15) ? -1 : 1;

    // wr[jj] pairs with ror_jj(H): k = ((c+kstep*jj)&15) + khalf
    // wr = -2 * 2log2e * Wh[k][u]   (r-fold weights)
    float wr[16];
    #pragma unroll
    for (int jj = 0; jj < 16; ++jj) {
        const int kj = ((c + kstep * jj) & 15) + khalf;
        wr[jj] = -2.0f * TWO_LOG2E * Wh[kj * UU + u];
    }
    // Shalf = sum_{k in this row's half} 2log2e*Wh[k][u] = -0.5 * sum wr
    float Shalf = 0.f;
    #pragma unroll
    for (int jj = 0; jj < 16; ++jj) Shalf += wr[jj];
    Shalf *= -0.5f;

    // ---- gather phase: 64 global_load_lds instrs, 8 tokens each ----
    const int sub = L >> 3;            // token-within-group
    const int q   = L & 7;             // 16-B chunk within the 128-B row
    for (int cc = 0; cc < 8; ++cc) {
        int tk8[8];
        #pragma unroll
        for (int i = 0; i < 8; ++i)
            tk8[i] = trow[cc * 64 + i * 8 + sub];
        #pragma unroll
        for (int i = 0; i < 8; ++i) {
            const float* src = P + (size_t)tk8[i] * UU + q * 4;
            float* dst = xs + (cc * 64 + i * 8) * UU;   // wave-uniform base
            __builtin_amdgcn_global_load_lds(
                (const __attribute__((address_space(1))) void*)src,
                (__attribute__((address_space(3))) void*)dst, 16, 0, 0);
        }
    }
    __syncthreads();   // drains vmcnt: all LDS rows resident

    // ---- scan ----
    float xr[8];
    #pragma unroll
    for (int j = 0; j < 8; ++j) xr[j] = xs[j * UU + u] + Shalf;

    float r = 0.5f;                    // h = 0  =>  r = 0.5

    for (int t = 0; t < TT; t += 8) {
        // block prefetch: 8 conflict-free ds_read_b32 (+Shalf off-chain)
        float xn[8];
        #pragma unroll
        for (int j = 0; j < 8; ++j)
            xn[j] = xs[((t + 8 + j) & (TT - 1)) * UU + u] + Shalf;

        #pragma unroll
        for (int j = 0; j < 8; ++j) {
            // A = rLo dup everywhere, Bv = rHi dup (v13-verified direction)
            float A  = r;
            float Bv = r;
            asm("s_nop 1\n\t"
                "v_permlane32_swap_b32 %0, %1\n\t"
                "s_nop 1"
                : "+v"(A), "+v"(Bv));
            // per-row k-half source
            float H = oddrow ? Bv : A;

            // 16 fused-DPP FMAs, 4 accs depth 4; base (0.5x'+S'half) in acc0
            float p0, p1, p2, p3;
            asm("s_nop 1\n\t"
                "v_fma_f32  %0, %4, %6, %5\n\t"
                "v_mul_f32  %1, %4, %7  row_ror:1\n\t"
                "v_mul_f32  %2, %4, %8  row_ror:2\n\t"
                "v_mul_f32  %3, %4, %9  row_ror:3\n\t"
                "v_fmac_f32 %0, %4, %10 row_ror:4\n\t"
                "v_fmac_f32 %1, %4, %11 row_ror:5\n\t"
                "v_fmac_f32 %2, %4, %12 row_ror:6\n\t"
                "v_fmac_f32 %3, %4, %13 row_ror:7\n\t"
                "v_fmac_f32 %0, %4, %14 row_ror:8\n\t"
                "v_fmac_f32 %1, %4, %15 row_ror:9\n\t"
                "v_fmac_f32 %2, %4, %16 row_ror:10\n\t"
                "v_fmac_f32 %3, %4, %17 row_ror:11\n\t"
                "v_fmac_f32 %0, %4, %18 row_ror:12\n\t"
                "v_fmac_f32 %1, %4, %19 row_ror:13\n\t"
                "v_fmac_f32 %2, %4, %20 row_ror:14\n\t"
                "v_fmac_f32 %3, %4, %21 row_ror:15"
                : "=&v"(p0), "=&v"(p1), "=&v"(p2), "=&v"(p3)
                : "v"(H), "v"(xr[j]),
                  "v"(wr[0]),  "v"(wr[1]),  "v"(wr[2]),  "v"(wr[3]),
                  "v"(wr[4]),  "v"(wr[5]),  "v"(wr[6]),  "v"(wr[7]),
                  "v"(wr[8]),  "v"(wr[9]),  "v"(wr[10]), "v"(wr[11]),
                  "v"(wr[12]), "v"(wr[13]), "v"(wr[14]), "v"(wr[15]));

            float p = (p0 + p1) + (p2 + p3);

            // combine across row pairs (0,1),(2,3): pA+pB is direction-immune
            float pA = p, pB = p;
            asm("s_nop 1\n\t"
                "v_permlane16_swap_b32 %0, %1\n\t"
                "s_nop 1"
                : "+v"(pA), "+v"(pB));

            float e = __builtin_amdgcn_exp2f(pA + pB);
            r = __builtin_amdgcn_rcpf(e + 1.0f);
            xr[j] = xn[j];
        }
    }

    float h = fmaf(-2.0f, r, 1.0f);    // materialize h once for the heads

    // ---- fused heads (layout-aware: h_k lives at lane (k&15)+((k>>4)<<5)) --
    const int jh = L & 15;
    float s = b1[jh];
    #pragma unroll
    for (int k = 0; k < UU; ++k) {
        float hk = rdlane(h, (k & 15) + ((k >> 4) << 5));
        s = fmaf(hk, W1[k * FF1 + jh], s);
    }
    float z = b2[0];
    #pragma unroll
    for (int jj = 0; jj < FF1; ++jj) {
        float yj = rdlane(s, jj);      // s duplicated across 16-rows
        z = fmaf(yj, W2[jj], z);
    }
    if (L == 0) {
        float e = __builtin_amdgcn_exp2f(-z * 1.4426950408889634f); // e^{-z}
        out[b] = __builtin_amdgcn_rcpf(1.0f + e);
    }
}

// ---------------------------------------------------------------------------
extern "C" void kernel_launch(void* const* d_in, const int* in_sizes, int n_in,
                              void* d_out, int out_size, void* d_ws, size_t ws_size,
                              hipStream_t stream) {
    const int*   tokens = (const int*)  d_in[0];
    const float* emb    = (const float*)d_in[1];
    const float* Wx     = (const float*)d_in[2];
    const float* Wh     = (const float*)d_in[3];
    const float* bias   = (const float*)d_in[4];
    const float* W1     = (const float*)d_in[5];
    const float* b1     = (const float*)d_in[6];
    const float* W2     = (const float*)d_in[7];
    const float* b2     = (const float*)d_in[8];
    float* out = (float*)d_out;

    const int vocab = in_sizes[1] / EE;        // 50000
    float* P = (float*)d_ws;                   // vocab*32*4 = 6.4 MB

    // A: 2048 single-wave blocks, ~25 rows each (8 waves/CU)
    proj_dpp<<<dim3(NWAVE), dim3(64), 0, stream>>>(
        emb, Wx, bias, P, vocab);

    // B: 1 batch row per wave -> 512 blocks x 64 threads (2 blocks/CU)
    scan_heads<<<dim3(BB), dim3(64), 0, stream>>>(
        tokens, P, Wh, W1, b1, W2, b2, out);
}